// Round 1
// baseline (843.346 us; speedup 1.0000x reference)
//
#include <hip/hip_runtime.h>

// Problem constants: N=4, C=64, H=128, W=128, KS=3, dilations {1,3,5}
// Inputs: x[4,64,128,128] f32, y[same], gen_w[1728,64], gen_b[1728],
//         fuse_w[64,256,3,3], fuse_b[64]. Out: [4,64,128,128] f32.

// Workspace layout (float offsets)
#define OFF_GW2 0u
#define SZ_GW2  (64u*1728u)            // gen_w transposed: [cc][tap*192 + bi*64 + c]
#define OFF_GB2 (OFF_GW2 + SZ_GW2)     // gen_b reordered:  [tap*192 + bi*64 + c]
#define SZ_GB2  1728u
#define OFF_FW2 (OFF_GB2 + SZ_GB2)     // fuse_w transposed: [(ic*9+k)*64 + oc]
#define SZ_FW2  (256u*9u*64u)
#define OFF_CAT (OFF_FW2 + SZ_FW2)     // cat (branches only): [n][192][128][128]
// total floats = 259776 + 12582912 = 12842688  (~51.4 MB)

__global__ void k_prep_gen(const float* __restrict__ gen_w,
                           const float* __restrict__ gen_b,
                           float* __restrict__ ws) {
    int idx = blockIdx.x * 256 + threadIdx.x;
    if (idx >= 1728 * 64) return;
    int o = idx >> 6, cc = idx & 63;
    int row = o / 9, tap = o % 9;          // row = bi*64 + c
    int op = tap * 192 + row;
    ws[OFF_GW2 + cc * 1728 + op] = gen_w[o * 64 + cc];
    if (cc == 0) ws[OFF_GB2 + op] = gen_b[o];
}

__global__ void k_prep_fuse(const float* __restrict__ fuse_w,
                            float* __restrict__ ws) {
    int idx = blockIdx.x * 256 + threadIdx.x;   // over 64*2304
    if (idx >= 64 * 2304) return;
    int oc = idx / 2304;
    int r  = idx % 2304;                        // ic*9 + k
    ws[OFF_FW2 + r * 64 + oc] = fuse_w[idx];
}

// Fused kernel-generation (per-pixel matvec) + 3-branch dilated depthwise conv.
// Grid: (W/32, H, N), block 192 (3 waves: wave = branch, lane = channel c).
__global__ __launch_bounds__(192) void k_gen_ddpm(const float* __restrict__ x,
                                                  const float* __restrict__ y,
                                                  float* __restrict__ ws) {
    __shared__ float ylds[64][32];
    const int w0 = blockIdx.x * 32;
    const int h  = blockIdx.y;
    const int n  = blockIdx.z;
    const int t  = threadIdx.x;

    for (int e = t; e < 64 * 32; e += 192) {
        int c2 = e >> 5, j = e & 31;
        ylds[c2][j] = y[(((size_t)n * 64 + c2) * 128 + h) * 128 + w0 + j];
    }
    __syncthreads();

    const int bi   = t >> 6;          // 0..2
    const int c    = t & 63;
    const int comb = bi * 64 + c;
    const int d    = 2 * bi + 1;      // dilation 1,3,5
    const float* gw2 = ws + OFF_GW2;
    const float* gb2 = ws + OFF_GB2;

    float kb[9];
#pragma unroll
    for (int tap = 0; tap < 9; ++tap) kb[tap] = gb2[tap * 192 + comb];

    const float* xc  = x + (((size_t)n * 64 + c) * 128) * 128;
    float* cat = ws + OFF_CAT + (((size_t)n * 192 + comb) * 128 + h) * 128;

    for (int p0 = 0; p0 < 32; p0 += 8) {
        float kk[9][8];
#pragma unroll
        for (int tap = 0; tap < 9; ++tap)
#pragma unroll
            for (int j = 0; j < 8; ++j) kk[tap][j] = kb[tap];

#pragma unroll 2
        for (int cc = 0; cc < 64; ++cc) {
            float gw[9];
#pragma unroll
            for (int tap = 0; tap < 9; ++tap)
                gw[tap] = gw2[cc * 1728 + tap * 192 + comb];   // coalesced over lanes
            float yv[8];
            *(float4*)&yv[0] = ((const float4*)&ylds[cc][p0])[0];  // broadcast
            *(float4*)&yv[4] = ((const float4*)&ylds[cc][p0])[1];
#pragma unroll
            for (int tap = 0; tap < 9; ++tap)
#pragma unroll
                for (int j = 0; j < 8; ++j)
                    kk[tap][j] = fmaf(gw[tap], yv[j], kk[tap][j]);
        }

        float acc[8];
#pragma unroll
        for (int j = 0; j < 8; ++j) acc[j] = 0.f;
#pragma unroll
        for (int tap = 0; tap < 9; ++tap) {
            const int ki = tap / 3, kj = tap % 3;
            const int hh = h + (ki - 1) * d;
            if (hh < 0 || hh >= 128) continue;
            const float* xr = xc + hh * 128;
#pragma unroll
            for (int j = 0; j < 8; ++j) {
                int wwp = w0 + p0 + j + (kj - 1) * d;
                if (wwp >= 0 && wwp < 128)
                    acc[j] = fmaf(kk[tap][j], xr[wwp], acc[j]);
            }
        }
#pragma unroll
        for (int j = 0; j < 8; ++j) cat[w0 + p0 + j] = acc[j];
    }
}

// Dense 3x3 conv 256->64 over cat (=[x | branches]) + bias.
// Grid: (W/64, H, N), block 256 (4 waves). lane = w, wave q owns oc q*16..q*16+15.
__global__ __launch_bounds__(256) void k_fuse(const float* __restrict__ x,
                                              const float* __restrict__ ws,
                                              const float* __restrict__ fuse_b,
                                              float* __restrict__ out) {
    __shared__ float xl[16][3][68];
    const int w0   = blockIdx.x * 64;
    const int h    = blockIdx.y;
    const int n    = blockIdx.z;
    const int t    = threadIdx.x;
    const int lane = t & 63;
    const int oc0  = __builtin_amdgcn_readfirstlane((t >> 6) * 16);
    const float* fw2 = ws + OFF_FW2;
    const float* cat = ws + OFF_CAT;

    float acc[16];
#pragma unroll
    for (int j = 0; j < 16; ++j) acc[j] = 0.f;

    for (int ic0 = 0; ic0 < 256; ic0 += 16) {
        __syncthreads();
        for (int e = t; e < 16 * 3 * 66; e += 256) {
            int icw = e / 198;
            int rem = e % 198;
            int r   = rem / 66;
            int col = rem % 66;
            int ic  = ic0 + icw;
            int hh  = h + r - 1;
            int wwp = w0 + col - 1;
            float v = 0.f;
            if (hh >= 0 && hh < 128 && wwp >= 0 && wwp < 128) {
                const float* src = (ic < 64)
                    ? (x   + (((size_t)n * 64  + ic)        * 128) * 128)
                    : (cat + (((size_t)n * 192 + (ic - 64)) * 128) * 128);
                v = src[hh * 128 + wwp];
            }
            xl[icw][r][col] = v;
        }
        __syncthreads();

#pragma unroll 1
        for (int icw = 0; icw < 16; ++icw) {
            const int base9 = (ic0 + icw) * 9;
#pragma unroll
            for (int kh = 0; kh < 3; ++kh) {
                float xv[3];
                xv[0] = xl[icw][kh][lane];
                xv[1] = xl[icw][kh][lane + 1];
                xv[2] = xl[icw][kh][lane + 2];
#pragma unroll
                for (int kw = 0; kw < 3; ++kw) {
                    const float* fp = fw2 + (base9 + kh * 3 + kw) * 64 + oc0;
                    float fv[16];
                    *(float4*)&fv[0]  = ((const float4*)fp)[0];
                    *(float4*)&fv[4]  = ((const float4*)fp)[1];
                    *(float4*)&fv[8]  = ((const float4*)fp)[2];
                    *(float4*)&fv[12] = ((const float4*)fp)[3];
                    const float xvv = xv[kw];
#pragma unroll
                    for (int j = 0; j < 16; ++j)
                        acc[j] = fmaf(fv[j], xvv, acc[j]);
                }
            }
        }
    }

#pragma unroll
    for (int j = 0; j < 16; ++j) {
        int oc = oc0 + j;
        out[(((size_t)n * 64 + oc) * 128 + h) * 128 + w0 + lane] = acc[j] + fuse_b[oc];
    }
}

extern "C" void kernel_launch(void* const* d_in, const int* in_sizes, int n_in,
                              void* d_out, int out_size, void* d_ws, size_t ws_size,
                              hipStream_t stream) {
    const float* x      = (const float*)d_in[0];
    const float* y      = (const float*)d_in[1];
    const float* gen_w  = (const float*)d_in[2];
    const float* gen_b  = (const float*)d_in[3];
    const float* fuse_w = (const float*)d_in[4];
    const float* fuse_b = (const float*)d_in[5];
    float* out = (float*)d_out;
    float* ws  = (float*)d_ws;

    k_prep_gen<<<dim3((1728 * 64 + 255) / 256), dim3(256), 0, stream>>>(gen_w, gen_b, ws);
    k_prep_fuse<<<dim3((64 * 2304 + 255) / 256), dim3(256), 0, stream>>>(fuse_w, ws);
    k_gen_ddpm<<<dim3(128 / 32, 128, 4), dim3(192), 0, stream>>>(x, y, ws);
    k_fuse<<<dim3(128 / 64, 128, 4), dim3(256), 0, stream>>>(x, ws, fuse_b, out);
}